// Round 7
// baseline (96.842 us; speedup 1.0000x reference)
//
#include <hip/hip_runtime.h>
#include <hip/hip_bf16.h>
#include <stdint.h>
#include <math.h>

#define D     256
#define NTOT  8192
#define NSRC  4096
#define NT    64                  // 64 tiles of 128 rows
#define NTRI  (NT * (NT + 1) / 2) // 2080 upper-tri tiles
#define PREPB 128                 // prep blocks (64 rows each)

using bf16x8 = __attribute__((ext_vector_type(8))) short;
using f32x4  = __attribute__((ext_vector_type(4))) float;

#if __has_builtin(__builtin_amdgcn_exp2f)
#define EXP2F __builtin_amdgcn_exp2f
#else
#define EXP2F exp2f
#endif

// workspace layout (bytes) — every region fully written before read each
// launch (no atomics, no fences, no counters) => poison-safe, deterministic.
#define OFF_XB   ((size_t)0)                        // 4 MB bf16 X
#define OFF_SQ   ((size_t)NTOT * D * 2)             // 8192 f32 row sq-norms
#define OFF_CP   (OFF_SQ + (size_t)NTOT * 4)        // colsum parts [PREPB][256]
#define OFF_SP   (OFF_CP + (size_t)PREPB * 256 * 4) // sq-sum parts [PREPB]
#define OFF_CF   (OFF_SP + (size_t)PREPB * 4)       // 1 f32 coeff (c4)
#define OFF_PT   (OFF_CF + 32)                      // per-tile partials [NTRI]
#define OFF_END  (OFF_PT + (size_t)NTRI * 4)

// ---- prep: f32 -> bf16 roundtrip, row sq-norms, per-block col/sq partials ----
__global__ __launch_bounds__(256) void prep_kernel(
    const float* __restrict__ src, const float* __restrict__ tgt,
    __hip_bfloat16* __restrict__ xb, float* __restrict__ sq,
    float* __restrict__ colpart, float* __restrict__ sqpart)
{
  __shared__ float scol4[4][256];
  __shared__ float sSl[4];
  const int tid = threadIdx.x, wave = tid >> 6, lane = tid & 63;
  const int row0 = blockIdx.x * 64 + wave * 16;    // blocks never straddle sides
  const float* p0 = (row0 < NSRC) ? (src + (size_t)row0 * D)
                                  : (tgt + (size_t)(row0 - NSRC) * D);
  float c0 = 0.f, c1 = 0.f, c2 = 0.f, c3 = 0.f, swave = 0.f;
  for (int rr = 0; rr < 16; ++rr) {
    const int row = row0 + rr;
    const float4 v = reinterpret_cast<const float4*>(p0 + (size_t)rr * D)[lane];
    const __hip_bfloat16 b0 = __float2bfloat16(v.x), b1 = __float2bfloat16(v.y),
                         b2 = __float2bfloat16(v.z), b3 = __float2bfloat16(v.w);
    ushort4 h;
    h.x = *(const unsigned short*)&b0; h.y = *(const unsigned short*)&b1;
    h.z = *(const unsigned short*)&b2; h.w = *(const unsigned short*)&b3;
    reinterpret_cast<ushort4*>(xb + (size_t)row * D)[lane] = h;
    const float f0 = __bfloat162float(b0), f1 = __bfloat162float(b1),
                f2 = __bfloat162float(b2), f3 = __bfloat162float(b3);
    c0 += f0; c1 += f1; c2 += f2; c3 += f3;
    float s = f0 * f0 + f1 * f1 + f2 * f2 + f3 * f3;
    #pragma unroll
    for (int off = 32; off > 0; off >>= 1) s += __shfl_down(s, off);
    if (lane == 0) { sq[row] = s; swave += s; }
  }
  scol4[wave][lane * 4 + 0] = c0;
  scol4[wave][lane * 4 + 1] = c1;
  scol4[wave][lane * 4 + 2] = c2;
  scol4[wave][lane * 4 + 3] = c3;
  if (lane == 0) sSl[wave] = swave;
  __syncthreads();
  colpart[blockIdx.x * 256 + tid] =
      scol4[0][tid] + scol4[1][tid] + scol4[2][tid] + scol4[3][tid];
  if (tid == 0) sqpart[blockIdx.x] = sSl[0] + sSl[1] + sSl[2] + sSl[3];
}

// ---- bw: reduce partials -> bandwidth coefficient c4 ----
__global__ __launch_bounds__(256) void bw_kernel(
    const float* __restrict__ colpart, const float* __restrict__ sqpart,
    float* __restrict__ cf)
{
  __shared__ float red[256];
  const int t = threadIdx.x;
  float cs = 0.f;
  for (int b = 0; b < PREPB; ++b) cs += colpart[b * 256 + t];  // coalesced
  red[t] = cs * cs;
  __syncthreads();
  for (int off = 128; off > 0; off >>= 1) {
    if (t < off) red[t] += red[t + off];
    __syncthreads();
  }
  const float s2 = red[0];
  __syncthreads();
  red[t] = (t < PREPB) ? sqpart[t] : 0.f;
  __syncthreads();
  for (int off = 128; off > 0; off >>= 1) {
    if (t < off) red[t] += red[t + off];
    __syncthreads();
  }
  if (t == 0) {
    const double sumd2 = 2.0 * (double)NTOT * (double)red[0] - 2.0 * (double)s2;
    const double bw = sumd2 / ((double)NTOT * (double)NTOT - (double)NTOT) / 4.0;
    cf[0] = (float)(-1.4426950408889634 / (bw * 16.0));  // c4
  }
}

// ---- main: triangular 128x128 tiles; LDS-FREE GEMM — fragments load straight
//      from L2-resident xb (4 MB), zero K-loop barriers, waves independent ----
__global__ __launch_bounds__(256) void pair_kernel(
    const __hip_bfloat16* __restrict__ xb, const float* __restrict__ sq,
    const float* __restrict__ cf, float* __restrict__ part)
{
  const int idx = blockIdx.x;
  const float rr = sqrtf(4160.25f - 2.0f * (float)idx);
  int bi = (int)(64.5f - rr);
  while (NT * (bi + 1) - (bi + 1) * bi / 2 <= idx) ++bi;
  while (NT * bi - bi * (bi - 1) / 2 > idx) --bi;
  const int bj = bi + (idx - (NT * bi - bi * (bi - 1) / 2));

  __shared__ float sqA[128], sqB[128];
  __shared__ float wsum[4];

  const int tid = threadIdx.x, wave = tid >> 6, lane = tid & 63;
  const int wr = wave >> 1, wc = wave & 1;

  const float c4 = cf[0];
  if (tid < 128) sqA[tid] = sq[bi * 128 + tid];
  else           sqB[tid - 128] = sq[bj * 128 + (tid - 128)];
  // (no barrier needed until epilogue reads sqA/sqB — ordered by the
  //  __syncthreads after the K-loop)

  // fragment pointers: lane reads row (base + frag*16 + (lane&15)),
  // k-bytes t*64 + (lane>>4)*16  — 16 rows x 64B segments per load (L2-served)
  const __hip_bfloat16* pA =
      xb + (size_t)(bi * 128 + wr * 64 + (lane & 15)) * D + (lane >> 4) * 8;
  const __hip_bfloat16* pB =
      xb + (size_t)(bj * 128 + wc * 64 + (lane & 15)) * D + (lane >> 4) * 8;

  f32x4 acc[4][4];
  #pragma unroll
  for (int mi = 0; mi < 4; ++mi)
    #pragma unroll
    for (int nj = 0; nj < 4; ++nj)
      acc[mi][nj] = (f32x4){0.f, 0.f, 0.f, 0.f};

  #pragma unroll
  for (int t = 0; t < 8; ++t) {            // K = 8 x 32
    bf16x8 af[4], bfr[4];
    #pragma unroll
    for (int mi = 0; mi < 4; ++mi)
      af[mi] = *(const bf16x8*)(pA + (size_t)mi * 16 * D + t * 32);
    #pragma unroll
    for (int nj = 0; nj < 4; ++nj)
      bfr[nj] = *(const bf16x8*)(pB + (size_t)nj * 16 * D + t * 32);
    #pragma unroll
    for (int mi = 0; mi < 4; ++mi)
      #pragma unroll
      for (int nj = 0; nj < 4; ++nj)
        acc[mi][nj] = __builtin_amdgcn_mfma_f32_16x16x32_bf16(
            af[mi], bfr[nj], acc[mi][nj], 0, 0, 0);
  }

  __syncthreads();   // sqA/sqB stores (pre-K-loop) ordered before epilogue reads

  // epilogue: d2 = si + sj - 2*gram; e4 = exp2(d2*c4); e_{t-1} = e_t^2
  const int r0 = (lane >> 4) * 4, cc = lane & 15;
  float sjv[4];
  #pragma unroll
  for (int nj = 0; nj < 4; ++nj) sjv[nj] = sqB[wc * 64 + nj * 16 + cc];
  float tsum = 0.f;
  #pragma unroll
  for (int mi = 0; mi < 4; ++mi) {
    #pragma unroll
    for (int r = 0; r < 4; ++r) {
      const float si = sqA[wr * 64 + mi * 16 + r0 + r];
      #pragma unroll
      for (int nj = 0; nj < 4; ++nj) {
        float d2 = fmaf(-2.f, acc[mi][nj][r], si + sjv[nj]);
        d2 = fmaxf(d2, 0.f);
        const float e4 = EXP2F(d2 * c4);
        const float e3 = e4 * e4, e2 = e3 * e3;
        const float e1 = e2 * e2, e0 = e1 * e1;
        tsum += ((e4 + e3) + (e2 + e1)) + e0;
      }
    }
  }
  #pragma unroll
  for (int off = 32; off > 0; off >>= 1) tsum += __shfl_down(tsum, off);
  if (lane == 0) wsum[wave] = tsum;
  __syncthreads();
  if (tid == 0) part[idx] = wsum[0] + wsum[1] + wsum[2] + wsum[3];
}

// ---- out: deterministic tree-reduce of tile partials ----
__global__ __launch_bounds__(256) void out_kernel(
    const float* __restrict__ part, float* __restrict__ out)
{
  __shared__ double red0[256], red1[256], red2[256];
  const int t = threadIdx.x;
  double a0 = 0.0, a1 = 0.0, a2 = 0.0;
  for (int j = t; j < NTRI; j += 256) {
    const float r1 = sqrtf(4160.25f - 2.0f * (float)j);
    int bi = (int)(64.5f - r1);
    while (NT * (bi + 1) - (bi + 1) * bi / 2 <= j) ++bi;
    while (NT * bi - bi * (bi - 1) / 2 > j) --bi;
    const int bj = bi + (j - (NT * bi - bi * (bi - 1) / 2));
    const double w = (bi == bj) ? 1.0 : 2.0;
    const double v = w * (double)part[j];
    if (bi >= 32) a1 += v;
    else if (bj >= 32) a2 += v;
    else a0 += v;
  }
  red0[t] = a0; red1[t] = a1; red2[t] = a2;
  __syncthreads();
  for (int off = 128; off > 0; off >>= 1) {
    if (t < off) {
      red0[t] += red0[t + off];
      red1[t] += red1[t + off];
      red2[t] += red2[t + off];
    }
    __syncthreads();
  }
  if (t == 0)
    out[0] = (float)((red0[0] + red1[0] - red2[0]) /
                     ((double)NSRC * (double)NSRC));
}

extern "C" void kernel_launch(void* const* d_in, const int* in_sizes, int n_in,
                              void* d_out, int out_size, void* d_ws, size_t ws_size,
                              hipStream_t stream) {
  (void)in_sizes; (void)n_in; (void)out_size; (void)ws_size;
  const float* src = (const float*)d_in[0];
  const float* tgt = (const float*)d_in[1];
  char* ws = (char*)d_ws;
  __hip_bfloat16* xb = (__hip_bfloat16*)(ws + OFF_XB);
  float* sq      = (float*)(ws + OFF_SQ);
  float* colpart = (float*)(ws + OFF_CP);
  float* sqpart  = (float*)(ws + OFF_SP);
  float* cf      = (float*)(ws + OFF_CF);
  float* part    = (float*)(ws + OFF_PT);

  prep_kernel<<<PREPB, 256, 0, stream>>>(src, tgt, xb, sq, colpart, sqpart);
  bw_kernel<<<1, 256, 0, stream>>>(colpart, sqpart, cf);
  pair_kernel<<<NTRI, 256, 0, stream>>>(xb, sq, cf, part);
  out_kernel<<<1, 256, 0, stream>>>(part, (float*)d_out);
}

// Round 8
// 56.335 us; speedup vs baseline: 1.7191x; 1.7191x over previous
//
#include <hip/hip_runtime.h>
#include <hip/hip_bf16.h>
#include <stdint.h>
#include <math.h>

#define D     256
#define NTOT  8192
#define NSRC  4096
#define NT    64                  // 64 tiles of 128 rows
#define NTRI  (NT * (NT + 1) / 2) // 2080 upper-tri tiles
#define PREPB 256                 // prep blocks (32 rows each)

using bf16x8 = __attribute__((ext_vector_type(8))) short;
using f32x4  = __attribute__((ext_vector_type(4))) float;

#define GLB_AS __attribute__((address_space(1)))
#define LDS_AS __attribute__((address_space(3)))

#if __has_builtin(__builtin_amdgcn_exp2f)
#define EXP2F __builtin_amdgcn_exp2f
#else
#define EXP2F exp2f
#endif

// workspace layout (bytes) — every region fully written before read each
// launch (no atomics, no fences, no counters) => poison-safe, deterministic.
#define OFF_XB   ((size_t)0)                        // 4 MB bf16 X
#define OFF_SQ   ((size_t)NTOT * D * 2)             // 8192 f32 row sq-norms
#define OFF_CP   (OFF_SQ + (size_t)NTOT * 4)        // colsum parts [PREPB][256]
#define OFF_SP   (OFF_CP + (size_t)PREPB * 256 * 4) // sq-sum parts [PREPB]
#define OFF_CF   (OFF_SP + (size_t)PREPB * 4)       // 1 f32 coeff (c4)
#define OFF_PT   (OFF_CF + 32)                      // per-tile partials [NTRI]
#define OFF_END  (OFF_PT + (size_t)NTRI * 4)

// ---- prep: f32 -> bf16 roundtrip, row sq-norms, per-block col/sq partials ----
__global__ __launch_bounds__(256) void prep_kernel(
    const float* __restrict__ src, const float* __restrict__ tgt,
    __hip_bfloat16* __restrict__ xb, float* __restrict__ sq,
    float* __restrict__ colpart, float* __restrict__ sqpart)
{
  __shared__ float scol4[4][256];
  __shared__ float sSl[4];
  const int tid = threadIdx.x, wave = tid >> 6, lane = tid & 63;
  const int row0 = blockIdx.x * 32 + wave * 8;     // blocks never straddle sides
  const float* p0 = (row0 < NSRC) ? (src + (size_t)row0 * D)
                                  : (tgt + (size_t)(row0 - NSRC) * D);
  float c0 = 0.f, c1 = 0.f, c2 = 0.f, c3 = 0.f, swave = 0.f;
  for (int rr = 0; rr < 8; ++rr) {
    const int row = row0 + rr;
    const float4 v = reinterpret_cast<const float4*>(p0 + (size_t)rr * D)[lane];
    const __hip_bfloat16 b0 = __float2bfloat16(v.x), b1 = __float2bfloat16(v.y),
                         b2 = __float2bfloat16(v.z), b3 = __float2bfloat16(v.w);
    ushort4 h;
    h.x = *(const unsigned short*)&b0; h.y = *(const unsigned short*)&b1;
    h.z = *(const unsigned short*)&b2; h.w = *(const unsigned short*)&b3;
    reinterpret_cast<ushort4*>(xb + (size_t)row * D)[lane] = h;
    const float f0 = __bfloat162float(b0), f1 = __bfloat162float(b1),
                f2 = __bfloat162float(b2), f3 = __bfloat162float(b3);
    c0 += f0; c1 += f1; c2 += f2; c3 += f3;
    float s = f0 * f0 + f1 * f1 + f2 * f2 + f3 * f3;
    #pragma unroll
    for (int off = 32; off > 0; off >>= 1) s += __shfl_down(s, off);
    if (lane == 0) { sq[row] = s; swave += s; }
  }
  scol4[wave][lane * 4 + 0] = c0;
  scol4[wave][lane * 4 + 1] = c1;
  scol4[wave][lane * 4 + 2] = c2;
  scol4[wave][lane * 4 + 3] = c3;
  if (lane == 0) sSl[wave] = swave;
  __syncthreads();
  colpart[blockIdx.x * 256 + tid] =
      scol4[0][tid] + scol4[1][tid] + scol4[2][tid] + scol4[3][tid];
  if (tid == 0) sqpart[blockIdx.x] = sSl[0] + sSl[1] + sSl[2] + sSl[3];
}

// ---- bw: reduce partials -> bandwidth coefficient c4 ----
__global__ __launch_bounds__(256) void bw_kernel(
    const float* __restrict__ colpart, const float* __restrict__ sqpart,
    float* __restrict__ cf)
{
  __shared__ float red[256];
  const int t = threadIdx.x;
  float cs = 0.f;
  for (int b = 0; b < PREPB; ++b) cs += colpart[b * 256 + t];  // coalesced
  red[t] = cs * cs;
  __syncthreads();
  for (int off = 128; off > 0; off >>= 1) {
    if (t < off) red[t] += red[t + off];
    __syncthreads();
  }
  const float s2 = red[0];
  __syncthreads();
  red[t] = (t < PREPB) ? sqpart[t] : 0.f;
  __syncthreads();
  for (int off = 128; off > 0; off >>= 1) {
    if (t < off) red[t] += red[t + off];
    __syncthreads();
  }
  if (t == 0) {
    const double sumd2 = 2.0 * (double)NTOT * (double)red[0] - 2.0 * (double)s2;
    const double bw = sumd2 / ((double)NTOT * (double)NTOT - (double)NTOT) / 4.0;
    cf[0] = (float)(-1.4426950408889634 / (bw * 16.0));  // c4
  }
}

// ---- main: triangular 128x128 tiles, SINGLE-buffer LDS (32 KB -> 4 blk/CU),
//      plain-barrier staged loop (TLP hides the drain), 1-exp epilogue ----
__global__ __launch_bounds__(256) void pair_kernel(
    const __hip_bfloat16* __restrict__ xb, const float* __restrict__ sq,
    const float* __restrict__ cf, float* __restrict__ part)
{
  // XCD swizzle: 2080 % 8 == 0, bijective; each XCD gets 260 consecutive
  // triangular indices (shared A-panels -> per-XCD L2 reuse)
  const int idx = (blockIdx.x & 7) * (NTRI / 8) + (blockIdx.x >> 3);
  const float rr = sqrtf(4160.25f - 2.0f * (float)idx);
  int bi = (int)(64.5f - rr);
  while (NT * (bi + 1) - (bi + 1) * bi / 2 <= idx) ++bi;
  while (NT * bi - bi * (bi - 1) / 2 > idx) --bi;
  const int bj = bi + (idx - (NT * bi - bi * (bi - 1) / 2));

  __shared__ __align__(16) short lA[128 * 64];   // single-buffered: 16 KB
  __shared__ __align__(16) short lB[128 * 64];   // 16 KB
  __shared__ float sqA[128], sqB[128], wsum[4];

  const int tid = threadIdx.x, wave = tid >> 6, lane = tid & 63;
  const int wr = wave >> 1, wc = wave & 1;

  const float c4 = cf[0];
  if (tid < 128) sqA[tid] = sq[bi * 128 + tid];
  else           sqB[tid - 128] = sq[bj * 128 + (tid - 128)];

  // gload_lds writes linear (wave base + lane*16); st-swizzled LDS layout via
  // pre-swizzled per-lane GLOBAL source column (rule 21: inverse-swz source +
  // swz read; XOR is an involution). Identical to R4 (verified, absmax 0).
  const int srow = lane >> 3;
  const int scol_e = ((lane & 7) ^ srow) * 8;
  const __hip_bfloat16* gA = xb + (size_t)(bi * 128 + wave * 8 + srow) * D + scol_e;
  const __hip_bfloat16* gB = xb + (size_t)(bj * 128 + wave * 8 + srow) * D + scol_e;
  char* ldsA = (char*)lA + (wave * 8) * 128;
  char* ldsB = (char*)lB + (wave * 8) * 128;

  f32x4 acc[4][4];
  #pragma unroll
  for (int mi = 0; mi < 4; ++mi)
    #pragma unroll
    for (int nj = 0; nj < 4; ++nj)
      acc[mi][nj] = (f32x4){0.f, 0.f, 0.f, 0.f};

  #pragma unroll
  for (int t = 0; t < 4; ++t) {
    #pragma unroll
    for (int q = 0; q < 4; ++q) {
      __builtin_amdgcn_global_load_lds(
          (const GLB_AS uint32_t*)(gA + (size_t)q * 32 * D + t * 64),
          (LDS_AS uint32_t*)(ldsA + q * 32 * 128), 16, 0, 0);
      __builtin_amdgcn_global_load_lds(
          (const GLB_AS uint32_t*)(gB + (size_t)q * 32 * D + t * 64),
          (LDS_AS uint32_t*)(ldsB + q * 32 * 128), 16, 0, 0);
    }
    __syncthreads();   // compiler drains vmcnt(0)+lgkmcnt(0) -> tile t resident

    #pragma unroll
    for (int ks = 0; ks < 2; ++ks) {
      bf16x8 af[4], bfr[4];
      const int kb = (ks * 32 + (lane >> 4) * 8) * 2;
      #pragma unroll
      for (int mi = 0; mi < 4; ++mi) {
        const int row = wr * 64 + mi * 16 + (lane & 15);
        af[mi] = *(const bf16x8*)((const char*)lA + row * 128 + (kb ^ ((row & 7) << 4)));
      }
      #pragma unroll
      for (int nj = 0; nj < 4; ++nj) {
        const int row = wc * 64 + nj * 16 + (lane & 15);
        bfr[nj] = *(const bf16x8*)((const char*)lB + row * 128 + (kb ^ ((row & 7) << 4)));
      }
      #pragma unroll
      for (int mi = 0; mi < 4; ++mi)
        #pragma unroll
        for (int nj = 0; nj < 4; ++nj)
          acc[mi][nj] = __builtin_amdgcn_mfma_f32_16x16x32_bf16(
              af[mi], bfr[nj], acc[mi][nj], 0, 0, 0);
    }
    if (t < 3) __syncthreads();   // all waves done reading before overwrite
  }

  // epilogue: d2 = si + sj - 2*gram; e4 = exp2(d2*c4); e_{t-1} = e_t^2
  const int r0 = (lane >> 4) * 4, cc = lane & 15;
  float sjv[4];
  #pragma unroll
  for (int nj = 0; nj < 4; ++nj) sjv[nj] = sqB[wc * 64 + nj * 16 + cc];
  float tsum = 0.f;
  #pragma unroll
  for (int mi = 0; mi < 4; ++mi) {
    #pragma unroll
    for (int r = 0; r < 4; ++r) {
      const float si = sqA[wr * 64 + mi * 16 + r0 + r];
      #pragma unroll
      for (int nj = 0; nj < 4; ++nj) {
        float d2 = fmaf(-2.f, acc[mi][nj][r], si + sjv[nj]);
        d2 = fmaxf(d2, 0.f);
        const float e4 = EXP2F(d2 * c4);
        const float e3 = e4 * e4, e2 = e3 * e3;
        const float e1 = e2 * e2, e0 = e1 * e1;
        tsum += ((e4 + e3) + (e2 + e1)) + e0;
      }
    }
  }
  #pragma unroll
  for (int off = 32; off > 0; off >>= 1) tsum += __shfl_down(tsum, off);
  if (lane == 0) wsum[wave] = tsum;
  __syncthreads();
  if (tid == 0) part[idx] = wsum[0] + wsum[1] + wsum[2] + wsum[3];
}

// ---- out: deterministic tree-reduce of tile partials ----
__global__ __launch_bounds__(256) void out_kernel(
    const float* __restrict__ part, float* __restrict__ out)
{
  __shared__ double red0[256], red1[256], red2[256];
  const int t = threadIdx.x;
  double a0 = 0.0, a1 = 0.0, a2 = 0.0;
  for (int j = t; j < NTRI; j += 256) {
    const float r1 = sqrtf(4160.25f - 2.0f * (float)j);
    int bi = (int)(64.5f - r1);
    while (NT * (bi + 1) - (bi + 1) * bi / 2 <= j) ++bi;
    while (NT * bi - bi * (bi - 1) / 2 > j) --bi;
    const int bj = bi + (j - (NT * bi - bi * (bi - 1) / 2));
    const double w = (bi == bj) ? 1.0 : 2.0;
    const double v = w * (double)part[j];
    if (bi >= 32) a1 += v;
    else if (bj >= 32) a2 += v;
    else a0 += v;
  }
  red0[t] = a0; red1[t] = a1; red2[t] = a2;
  __syncthreads();
  for (int off = 128; off > 0; off >>= 1) {
    if (t < off) {
      red0[t] += red0[t + off];
      red1[t] += red1[t + off];
      red2[t] += red2[t + off];
    }
    __syncthreads();
  }
  if (t == 0)
    out[0] = (float)((red0[0] + red1[0] - red2[0]) /
                     ((double)NSRC * (double)NSRC));
}

extern "C" void kernel_launch(void* const* d_in, const int* in_sizes, int n_in,
                              void* d_out, int out_size, void* d_ws, size_t ws_size,
                              hipStream_t stream) {
  (void)in_sizes; (void)n_in; (void)out_size; (void)ws_size;
  const float* src = (const float*)d_in[0];
  const float* tgt = (const float*)d_in[1];
  char* ws = (char*)d_ws;
  __hip_bfloat16* xb = (__hip_bfloat16*)(ws + OFF_XB);
  float* sq      = (float*)(ws + OFF_SQ);
  float* colpart = (float*)(ws + OFF_CP);
  float* sqpart  = (float*)(ws + OFF_SP);
  float* cf      = (float*)(ws + OFF_CF);
  float* part    = (float*)(ws + OFF_PT);

  prep_kernel<<<PREPB, 256, 0, stream>>>(src, tgt, xb, sq, colpart, sqpart);
  bw_kernel<<<1, 256, 0, stream>>>(colpart, sqpart, cf);
  pair_kernel<<<NTRI, 256, 0, stream>>>(xb, sq, cf, part);
  out_kernel<<<1, 256, 0, stream>>>(part, (float*)d_out);
}

// Round 10
// 52.349 us; speedup vs baseline: 1.8499x; 1.0761x over previous
//
#include <hip/hip_runtime.h>
#include <hip/hip_bf16.h>
#include <stdint.h>
#include <math.h>

#define D     256
#define NTOT  8192
#define NSRC  4096
#define NT    64                  // 64 tiles of 128 rows
#define NTRI  (NT * (NT + 1) / 2) // 2080 upper-tri tiles
#define PREPB 256                 // prep blocks (32 rows each)

using f32x4 = __attribute__((ext_vector_type(4))) float;

#define GLB_AS __attribute__((address_space(1)))
#define LDS_AS __attribute__((address_space(3)))

#if __has_builtin(__builtin_amdgcn_exp2f)
#define EXP2F __builtin_amdgcn_exp2f
#else
#define EXP2F exp2f
#endif

// ---- manual OCP e4m3 converters (RNE, FTZ below 2^-7, clamp 448) ----
__device__ inline unsigned char f32_to_e4m3(float v) {
  uint32_t u = __float_as_uint(v);
  uint32_t s = (u >> 24) & 0x80u;
  uint32_t m = u & 0x7FFFFFFFu;
  if (m <= 0x3C000000u) return (unsigned char)s;            // |v| <= 2^-7 -> 0
  if (m <  0x3C800000u) return (unsigned char)(s | 0x08u);  // -> min normal 2^-6
  if (m >= 0x43F00000u) return (unsigned char)(s | 0x7Eu);  // clamp to 448
  uint32_t r = m + 0x0007FFFFu + ((m >> 20) & 1u);          // RNE to 3 mant bits
  uint32_t e = (r >> 23) - 127u + 7u;                       // 1..15
  return (unsigned char)(s | (e << 3) | ((r >> 20) & 7u));
}
__device__ inline float e4m3_to_f32(unsigned char q) {
  uint32_t s = ((uint32_t)(q & 0x80u)) << 24;
  uint32_t em = q & 0x7Fu;
  if (em == 0) return __uint_as_float(s);                   // we never emit denormals
  uint32_t e = (em >> 3) + 120u;                            // -7 + 127
  return __uint_as_float(s | (e << 23) | ((em & 7u) << 20));
}

// workspace layout (bytes) — every region fully written before read each
// launch (no atomics, no fences, no counters) => poison-safe, deterministic.
#define OFF_XB   ((size_t)0)                        // 2 MB fp8 X
#define OFF_SQ   ((size_t)NTOT * D)                 // 8192 f32 row sq-norms
#define OFF_CP   (OFF_SQ + (size_t)NTOT * 4)        // colsum parts [PREPB][256]
#define OFF_SP   (OFF_CP + (size_t)PREPB * 256 * 4) // sq-sum parts [PREPB]
#define OFF_CF   (OFF_SP + (size_t)PREPB * 4)       // 1 f32 coeff (c4)
#define OFF_PT   (OFF_CF + 32)                      // per-tile partials [NTRI]
#define OFF_END  (OFF_PT + (size_t)NTRI * 4)

// ---- prep: f32 -> fp8 roundtrip, row sq-norms, per-block col/sq partials ----
__global__ __launch_bounds__(256) void prep_kernel(
    const float* __restrict__ src, const float* __restrict__ tgt,
    unsigned char* __restrict__ xb, float* __restrict__ sq,
    float* __restrict__ colpart, float* __restrict__ sqpart)
{
  __shared__ float scol4[4][256];
  __shared__ float sSl[4];
  const int tid = threadIdx.x, wave = tid >> 6, lane = tid & 63;
  const int row0 = blockIdx.x * 32 + wave * 8;     // blocks never straddle sides
  const float* p0 = (row0 < NSRC) ? (src + (size_t)row0 * D)
                                  : (tgt + (size_t)(row0 - NSRC) * D);
  float c0 = 0.f, c1 = 0.f, c2 = 0.f, c3 = 0.f, swave = 0.f;
  for (int rr = 0; rr < 8; ++rr) {
    const int row = row0 + rr;
    const float4 v = reinterpret_cast<const float4*>(p0 + (size_t)rr * D)[lane];
    uchar4 h;
    h.x = f32_to_e4m3(v.x); h.y = f32_to_e4m3(v.y);
    h.z = f32_to_e4m3(v.z); h.w = f32_to_e4m3(v.w);
    reinterpret_cast<uchar4*>(xb + (size_t)row * D)[lane] = h;
    const float f0 = e4m3_to_f32(h.x), f1 = e4m3_to_f32(h.y),
                f2 = e4m3_to_f32(h.z), f3 = e4m3_to_f32(h.w);
    c0 += f0; c1 += f1; c2 += f2; c3 += f3;
    float s = f0 * f0 + f1 * f1 + f2 * f2 + f3 * f3;
    #pragma unroll
    for (int off = 32; off > 0; off >>= 1) s += __shfl_down(s, off);
    if (lane == 0) { sq[row] = s; swave += s; }
  }
  scol4[wave][lane * 4 + 0] = c0;
  scol4[wave][lane * 4 + 1] = c1;
  scol4[wave][lane * 4 + 2] = c2;
  scol4[wave][lane * 4 + 3] = c3;
  if (lane == 0) sSl[wave] = swave;
  __syncthreads();
  colpart[blockIdx.x * 256 + tid] =
      scol4[0][tid] + scol4[1][tid] + scol4[2][tid] + scol4[3][tid];
  if (tid == 0) sqpart[blockIdx.x] = sSl[0] + sSl[1] + sSl[2] + sSl[3];
}

// ---- bw: reduce partials -> bandwidth coefficient c4 ----
__global__ __launch_bounds__(256) void bw_kernel(
    const float* __restrict__ colpart, const float* __restrict__ sqpart,
    float* __restrict__ cf)
{
  __shared__ float red[256];
  const int t = threadIdx.x;
  float cs = 0.f;
  for (int b = 0; b < PREPB; ++b) cs += colpart[b * 256 + t];  // coalesced
  red[t] = cs * cs;
  __syncthreads();
  for (int off = 128; off > 0; off >>= 1) {
    if (t < off) red[t] += red[t + off];
    __syncthreads();
  }
  const float s2 = red[0];
  __syncthreads();
  red[t] = (t < PREPB) ? sqpart[t] : 0.f;
  __syncthreads();
  for (int off = 128; off > 0; off >>= 1) {
    if (t < off) red[t] += red[t + off];
    __syncthreads();
  }
  if (t == 0) {
    const double sumd2 = 2.0 * (double)NTOT * (double)red[0] - 2.0 * (double)s2;
    const double bw = sumd2 / ((double)NTOT * (double)NTOT - (double)NTOT) / 4.0;
    cf[0] = (float)(-1.4426950408889634 / (bw * 16.0));  // c4
  }
}

// ---- main: triangular 128x128 tiles, fp8 MFMA, BK=128 (2 K-tiles, 3 barriers),
//      32 KB single-buffer LDS (4 blk/CU), 1-exp epilogue ----
__global__ __launch_bounds__(256) void pair_kernel(
    const unsigned char* __restrict__ xb, const float* __restrict__ sq,
    const float* __restrict__ cf, float* __restrict__ part)
{
  // XCD slab map (bijective, NTRI%8==0): L2 locality per XCD
  const int idx = (blockIdx.x & 7) * (NTRI / 8) + (blockIdx.x >> 3);
  const float rr = sqrtf(4160.25f - 2.0f * (float)idx);
  int bi = (int)(64.5f - rr);
  while (NT * (bi + 1) - (bi + 1) * bi / 2 <= idx) ++bi;
  while (NT * bi - bi * (bi - 1) / 2 > idx) --bi;
  const int bj = bi + (idx - (NT * bi - bi * (bi - 1) / 2));

  __shared__ __align__(16) unsigned char lA[128 * 128];  // 16 KB (BK=128 fp8)
  __shared__ __align__(16) unsigned char lB[128 * 128];  // 16 KB
  __shared__ float sqA[128], sqB[128], wsum[4];

  const int tid = threadIdx.x, wave = tid >> 6, lane = tid & 63;
  const int wr = wave >> 1, wc = wave & 1;

  const float c4 = cf[0];
  if (tid < 128) sqA[tid] = sq[bi * 128 + tid];
  else           sqB[tid - 128] = sq[bj * 128 + (tid - 128)];

  // Staging (rule 21): gload_lds dest is linear (wave base + lane*16); the
  // 16B-slot XOR swizzle LDS[row][s] = G[row][s ^ (row&7)] comes from the
  // pre-swizzled per-lane GLOBAL source slot. row&7 == lane>>3 here.
  const unsigned char* gA0 =
      xb + (size_t)(bi * 128 + wave * 32 + (lane >> 3)) * D + ((lane & 7) ^ (lane >> 3)) * 16;
  const unsigned char* gB0 =
      xb + (size_t)(bj * 128 + wave * 32 + (lane >> 3)) * D + ((lane & 7) ^ (lane >> 3)) * 16;
  char* dA = (char*)lA + wave * 4096;
  char* dB = (char*)lB + wave * 4096;

#define STAGE(t) do {                                                        \
    _Pragma("unroll")                                                        \
    for (int q = 0; q < 4; ++q) {                                            \
      __builtin_amdgcn_global_load_lds(                                      \
          (const GLB_AS uint32_t*)(gA0 + (size_t)q * 8 * D + (t) * 128),     \
          (LDS_AS uint32_t*)(dA + q * 1024), 16, 0, 0);                      \
      __builtin_amdgcn_global_load_lds(                                      \
          (const GLB_AS uint32_t*)(gB0 + (size_t)q * 8 * D + (t) * 128),     \
          (LDS_AS uint32_t*)(dB + q * 1024), 16, 0, 0);                      \
    } } while (0)

  f32x4 acc[4][4];
  #pragma unroll
  for (int mi = 0; mi < 4; ++mi)
    #pragma unroll
    for (int nj = 0; nj < 4; ++nj)
      acc[mi][nj] = (f32x4){0.f, 0.f, 0.f, 0.f};

  // fragment read geometry: row = base + mi*16 + (lane&15); k-byte
  // c = ks*32 + (lane>>4)*8 -> swizzled byte = ((c>>4)^(row&7))<<4 | (c&8)
  const int g = lane >> 4, r7 = lane & 7, rlow = lane & 15;
  const int off8 = (g & 1) * 8, ghalf = g >> 1;

  #pragma unroll
  for (int t = 0; t < 2; ++t) {            // 2 K-tiles of 128
    STAGE(t);
    __syncthreads();                       // drain: tile t resident
    #pragma unroll
    for (int ks = 0; ks < 4; ++ks) {       // K = 4 x 32 within tile
      const int slot = (2 * ks + ghalf);
      long af[4], bf[4];
      #pragma unroll
      for (int mi = 0; mi < 4; ++mi) {
        const int rowA = wr * 64 + mi * 16 + rlow;
        af[mi] = *(const long*)((const char*)lA + rowA * 128 +
                                (((slot ^ r7)) << 4) + off8);
      }
      #pragma unroll
      for (int nj = 0; nj < 4; ++nj) {
        const int rowB = wc * 64 + nj * 16 + rlow;
        bf[nj] = *(const long*)((const char*)lB + rowB * 128 +
                                (((slot ^ r7)) << 4) + off8);
      }
      #pragma unroll
      for (int mi = 0; mi < 4; ++mi)
        #pragma unroll
        for (int nj = 0; nj < 4; ++nj)
          acc[mi][nj] = __builtin_amdgcn_mfma_f32_16x16x32_fp8_fp8(
              af[mi], bf[nj], acc[mi][nj], 0, 0, 0);
    }
    if (t == 0) __syncthreads();           // readers done before overwrite
  }
#undef STAGE

  // epilogue: d2 = si + sj - 2*gram; e4 = exp2(d2*c4); e_{t-1} = e_t^2
  const int r0c = (lane >> 4) * 4, cc = lane & 15;
  float sjv[4];
  #pragma unroll
  for (int nj = 0; nj < 4; ++nj) sjv[nj] = sqB[wc * 64 + nj * 16 + cc];
  float tsum = 0.f;
  #pragma unroll
  for (int mi = 0; mi < 4; ++mi) {
    #pragma unroll
    for (int r = 0; r < 4; ++r) {
      const float si = sqA[wr * 64 + mi * 16 + r0c + r];
      #pragma unroll
      for (int nj = 0; nj < 4; ++nj) {
        float d2 = fmaf(-2.f, acc[mi][nj][r], si + sjv[nj]);
        d2 = fmaxf(d2, 0.f);
        const float e4 = EXP2F(d2 * c4);
        const float e3 = e4 * e4, e2 = e3 * e3;
        const float e1 = e2 * e2, e0 = e1 * e1;
        tsum += ((e4 + e3) + (e2 + e1)) + e0;
      }
    }
  }
  #pragma unroll
  for (int off = 32; off > 0; off >>= 1) tsum += __shfl_down(tsum, off);
  if (lane == 0) wsum[wave] = tsum;
  __syncthreads();
  if (tid == 0) part[idx] = wsum[0] + wsum[1] + wsum[2] + wsum[3];
}

// ---- out: deterministic tree-reduce of tile partials ----
__global__ __launch_bounds__(256) void out_kernel(
    const float* __restrict__ part, float* __restrict__ out)
{
  __shared__ double red0[256], red1[256], red2[256];
  const int t = threadIdx.x;
  double a0 = 0.0, a1 = 0.0, a2 = 0.0;
  for (int j = t; j < NTRI; j += 256) {
    const float r1 = sqrtf(4160.25f - 2.0f * (float)j);
    int bi = (int)(64.5f - r1);
    while (NT * (bi + 1) - (bi + 1) * bi / 2 <= j) ++bi;
    while (NT * bi - bi * (bi - 1) / 2 > j) --bi;
    const int bj = bi + (j - (NT * bi - bi * (bi - 1) / 2));
    const double w = (bi == bj) ? 1.0 : 2.0;
    const double v = w * (double)part[j];
    if (bi >= 32) a1 += v;
    else if (bj >= 32) a2 += v;
    else a0 += v;
  }
  red0[t] = a0; red1[t] = a1; red2[t] = a2;
  __syncthreads();
  for (int off = 128; off > 0; off >>= 1) {
    if (t < off) {
      red0[t] += red0[t + off];
      red1[t] += red1[t + off];
      red2[t] += red2[t + off];
    }
    __syncthreads();
  }
  if (t == 0)
    out[0] = (float)((red0[0] + red1[0] - red2[0]) /
                     ((double)NSRC * (double)NSRC));
}

extern "C" void kernel_launch(void* const* d_in, const int* in_sizes, int n_in,
                              void* d_out, int out_size, void* d_ws, size_t ws_size,
                              hipStream_t stream) {
  (void)in_sizes; (void)n_in; (void)out_size; (void)ws_size;
  const float* src = (const float*)d_in[0];
  const float* tgt = (const float*)d_in[1];
  char* ws = (char*)d_ws;
  unsigned char* xb = (unsigned char*)(ws + OFF_XB);
  float* sq      = (float*)(ws + OFF_SQ);
  float* colpart = (float*)(ws + OFF_CP);
  float* sqpart  = (float*)(ws + OFF_SP);
  float* cf      = (float*)(ws + OFF_CF);
  float* part    = (float*)(ws + OFF_PT);

  prep_kernel<<<PREPB, 256, 0, stream>>>(src, tgt, xb, sq, colpart, sqpart);
  bw_kernel<<<1, 256, 0, stream>>>(colpart, sqpart, cf);
  pair_kernel<<<NTRI, 256, 0, stream>>>(xb, sq, cf, part);
  out_kernel<<<1, 256, 0, stream>>>(part, (float*)d_out);
}